// Round 1
// baseline (309.211 us; speedup 1.0000x reference)
//
#include <hip/hip_runtime.h>
#include <math.h>

#define KS    15
#define HALF  7
#define NORI  8
#define HW    256
#define TW    64
#define TH    16
#define TWP   (TW + KS - 1)   // 78
#define THP   (TH + KS - 1)   // 30

// ---------------------------------------------------------------------------
// Kernel A: build the 8 normalized Gabor kernels into ws, transposed [tap][o]
// One block of 512 threads = 8 waves; wave o handles orientation o.
// ---------------------------------------------------------------------------
__global__ __launch_bounds__(512) void gabor_make_kernels(
    const float* __restrict__ theta, const float* __restrict__ sigma,
    const float* __restrict__ lambd, const float* __restrict__ gamma,
    const float* __restrict__ psi,   float* __restrict__ ktr)
{
    const int lane = threadIdx.x & 63;
    const int o    = threadIdx.x >> 6;   // 0..7

    const float th = theta[o];
    const float sg = fmaxf(sigma[o], 1.0f);
    const float lb = fmaxf(lambd[o], 2.0f);
    const float gm = fminf(fmaxf(gamma[o], 0.1f), 1.0f);
    const float ps = psi[o];

    const float ct = cosf(th), st = sinf(th);
    const float inv_sg2 = 1.0f / (sg * sg);
    const float gm2 = gm * gm;
    const float twopi_over_lb = 6.283185307179586f / lb;

    float vals[4];
    float sum = 0.0f, sumsq = 0.0f;
    #pragma unroll
    for (int j = 0; j < 4; ++j) {
        const int t = lane + j * 64;
        float v = 0.0f;
        if (t < KS * KS) {
            const int ky = t / KS, kx = t % KS;
            const float yg = (float)(ky - HALF);
            const float xg = (float)(kx - HALF);
            const float x_th =  xg * ct + yg * st;
            const float y_th = -xg * st + yg * ct;
            const float g = expf(-0.5f * (x_th * x_th + gm2 * y_th * y_th) * inv_sg2);
            const float s = cosf(twopi_over_lb * x_th + ps);
            v = g * s;
            sum   += v;
            sumsq += v * v;
        }
        vals[j] = v;
    }

    // wave-64 reduction
    #pragma unroll
    for (int off = 32; off > 0; off >>= 1) {
        sum   += __shfl_down(sum,   off);
        sumsq += __shfl_down(sumsq, off);
    }
    sum   = __shfl(sum,   0);
    sumsq = __shfl(sumsq, 0);

    const float n    = (float)(KS * KS);          // 225
    const float mean = sum / n;
    const float var  = (sumsq - sum * sum / n) / (n - 1.0f);  // ddof=1
    const float inv  = 1.0f / (sqrtf(var) + 1e-8f);

    #pragma unroll
    for (int j = 0; j < 4; ++j) {
        const int t = lane + j * 64;
        if (t < KS * KS)
            ktr[t * NORI + o] = (vals[j] - mean) * inv;   // transposed layout
    }
}

// ---------------------------------------------------------------------------
// Kernel B: fused channel-sum + 15x15 conv, 8 orientations per thread.
// Block = 256 threads, output tile TH x TW (16 x 64) per block.
// Thread (tx = tid&63, tyq = tid>>6) computes rows tyq*4 .. tyq*4+3, col tx.
// ---------------------------------------------------------------------------
__global__ __launch_bounds__(256) void gabor_conv(
    const float* __restrict__ x, const float* __restrict__ ktr,
    float* __restrict__ out)
{
    __shared__ float kl[KS * KS * NORI];   // 7200 B, [tap][o]
    __shared__ float tile[THP * TWP];      // 9360 B

    const int tid = threadIdx.x;
    const int n  = blockIdx.z;
    const int h0 = blockIdx.y * TH;
    const int w0 = blockIdx.x * TW;

    // load kernels into LDS
    for (int i = tid; i < KS * KS * NORI; i += 256)
        kl[i] = ktr[i];

    // stage input tile with fused channel sum + zero padding
    const float* xn = x + (size_t)n * 3 * HW * HW;
    for (int i = tid; i < THP * TWP; i += 256) {
        const int r = i / TWP, c = i % TWP;
        const int h = h0 + r - HALF;
        const int w = w0 + c - HALF;
        float v = 0.0f;
        if (h >= 0 && h < HW && w >= 0 && w < HW) {
            const int base = h * HW + w;
            v = xn[base] + xn[base + HW * HW] + xn[base + 2 * HW * HW];
        }
        tile[i] = v;
    }
    __syncthreads();

    const int tx   = tid & 63;
    const int rowb = (tid >> 6) * 4;   // rows rowb .. rowb+3

    float acc[4][NORI];
    #pragma unroll
    for (int i = 0; i < 4; ++i)
        #pragma unroll
        for (int o = 0; o < NORI; ++o)
            acc[i][o] = 0.0f;

    #pragma unroll 1
    for (int ky = 0; ky < KS; ++ky) {
        const float* trow = &tile[(rowb + ky) * TWP + tx];
        const float* krow = &kl[ky * KS * NORI];
        #pragma unroll
        for (int kx = 0; kx < KS; ++kx) {
            const float4 ka = *(const float4*)&krow[kx * NORI];
            const float4 kb = *(const float4*)&krow[kx * NORI + 4];
            #pragma unroll
            for (int i = 0; i < 4; ++i) {
                const float v = trow[i * TWP + kx];
                acc[i][0] = fmaf(v, ka.x, acc[i][0]);
                acc[i][1] = fmaf(v, ka.y, acc[i][1]);
                acc[i][2] = fmaf(v, ka.z, acc[i][2]);
                acc[i][3] = fmaf(v, ka.w, acc[i][3]);
                acc[i][4] = fmaf(v, kb.x, acc[i][4]);
                acc[i][5] = fmaf(v, kb.y, acc[i][5]);
                acc[i][6] = fmaf(v, kb.z, acc[i][6]);
                acc[i][7] = fmaf(v, kb.w, acc[i][7]);
            }
        }
    }

    // write out[n][o][h][w]
    float* on = out + (size_t)n * NORI * HW * HW;
    #pragma unroll
    for (int i = 0; i < 4; ++i) {
        const int h = h0 + rowb + i;
        const int w = w0 + tx;
        #pragma unroll
        for (int o = 0; o < NORI; ++o)
            on[(size_t)o * HW * HW + h * HW + w] = acc[i][o];
    }
}

extern "C" void kernel_launch(void* const* d_in, const int* in_sizes, int n_in,
                              void* d_out, int out_size, void* d_ws, size_t ws_size,
                              hipStream_t stream) {
    const float* x     = (const float*)d_in[0];
    const float* theta = (const float*)d_in[1];
    const float* sigma = (const float*)d_in[2];
    const float* lambd = (const float*)d_in[3];
    const float* gamma = (const float*)d_in[4];
    const float* psi   = (const float*)d_in[5];
    float* out = (float*)d_out;
    float* ktr = (float*)d_ws;   // 15*15*8 floats = 7200 B

    gabor_make_kernels<<<1, 512, 0, stream>>>(theta, sigma, lambd, gamma, psi, ktr);

    dim3 grid(HW / TW, HW / TH, 64);   // (4, 16, 64)
    gabor_conv<<<grid, 256, 0, stream>>>(x, ktr, out);
}

// Round 2
// 208.202 us; speedup vs baseline: 1.4852x; 1.4852x over previous
//
#include <hip/hip_runtime.h>
#include <math.h>

#define KS    15
#define HALF  7
#define NORI  8
#define HW    256
#define TW    64          // output cols per block
#define TH    64          // output rows per block
#define WT    96          // padded tile width (bf16 elements); 48 words/row
#define WROW  48          // words per tile row
#define RT    80          // tile rows staged (TH + 16)
#define TWORDS (RT * WROW) // 3840 words per copy

typedef __attribute__((ext_vector_type(8))) short  short8;
typedef __attribute__((ext_vector_type(4))) float  floatx4;

union FragU { uint4 u4; short8 s8; };

__device__ __forceinline__ ushort f2bf(float f) {
    union { float f; uint u; } a; a.f = f;
    return (ushort)((a.u + 0x7FFFu + ((a.u >> 16) & 1u)) >> 16);
}

// out[img][o][h][w] = sum_{ky,kx} K[o][ky][kx] * xsum[img][h+ky-7][w+kx-7]
__global__ __launch_bounds__(256) void gabor_mfma(
    const float* __restrict__ x,
    const float* __restrict__ theta, const float* __restrict__ sigma,
    const float* __restrict__ lambd, const float* __restrict__ gamma,
    const float* __restrict__ psi,
    float* __restrict__ out)
{
    __shared__ uint   tile[2 * TWORDS];   // 2 copies (col-shift 0 / 1), bf16 pairs
    __shared__ ushort kwa[16 * 16 * 16];  // weights [ori16][ky16][kx16], bf16 bits

    const int tid  = threadIdx.x;
    const int img  = blockIdx.z;
    const int h0   = blockIdx.y * TH;
    const int w0   = blockIdx.x * TW;
    const int lane = tid & 63;
    const int wave = tid >> 6;

    // ---- phase 1: zero the (padded) weight array ----
    for (int i = tid; i < 16 * 16 * 16; i += 256) kwa[i] = 0;
    __syncthreads();

    // ---- phase 2a: compute Gabor weights (wave w -> orientations 2w, 2w+1) ----
    #pragma unroll 1
    for (int oo = 0; oo < 2; ++oo) {
        const int o = wave * 2 + oo;
        const float th = theta[o];
        const float sg = fmaxf(sigma[o], 1.0f);
        const float lb = fmaxf(lambd[o], 2.0f);
        const float gm = fminf(fmaxf(gamma[o], 0.1f), 1.0f);
        const float ps = psi[o];
        const float ct = cosf(th), st = sinf(th);
        const float inv_sg2 = 1.0f / (sg * sg);
        const float gm2 = gm * gm;
        const float wfreq = 6.283185307179586f / lb;

        float vals[4];
        float sum = 0.0f, sumsq = 0.0f;
        #pragma unroll
        for (int j = 0; j < 4; ++j) {
            const int t = lane + j * 64;
            float v = 0.0f;
            if (t < KS * KS) {
                const int ky = t / KS, kx = t % KS;
                const float yg = (float)(ky - HALF);
                const float xg = (float)(kx - HALF);
                const float x_th =  xg * ct + yg * st;
                const float y_th = -xg * st + yg * ct;
                const float g = expf(-0.5f * (x_th * x_th + gm2 * y_th * y_th) * inv_sg2);
                v = g * cosf(wfreq * x_th + ps);
                sum += v; sumsq += v * v;
            }
            vals[j] = v;
        }
        #pragma unroll
        for (int off = 32; off > 0; off >>= 1) {
            sum   += __shfl_down(sum,   off);
            sumsq += __shfl_down(sumsq, off);
        }
        sum = __shfl(sum, 0); sumsq = __shfl(sumsq, 0);
        const float nn   = (float)(KS * KS);
        const float mean = sum / nn;
        const float var  = (sumsq - sum * sum / nn) / (nn - 1.0f);
        const float inv  = 1.0f / (sqrtf(var) + 1e-8f);
        #pragma unroll
        for (int j = 0; j < 4; ++j) {
            const int t = lane + j * 64;
            if (t < KS * KS) {
                const int ky = t / KS, kx = t % KS;
                kwa[(o * 16 + ky) * 16 + kx] = f2bf((vals[j] - mean) * inv);
            }
        }
    }

    // ---- phase 2b: stage channel-summed input tile as bf16, 2 shifted copies ----
    {
        const float* xim = x + ((size_t)img * 3) * HW * HW;
        for (int i = tid; i < 2 * TWORDS; i += 256) {
            const int s  = (i >= TWORDS) ? 1 : 0;
            const int j  = i - s * TWORDS;
            const int r  = j / WROW, wc = j - r * WROW;
            const int h  = h0 + r - HALF;
            const int wb = w0 + 2 * wc + s - HALF;   // global col of low element
            float v0 = 0.0f, v1 = 0.0f;
            if (h >= 0 && h < HW) {
                const float* xr = xim + h * HW;
                if (wb >= 0 && wb < HW)
                    v0 = xr[wb] + xr[wb + HW * HW] + xr[wb + 2 * HW * HW];
                const int wb1 = wb + 1;
                if (wb1 >= 0 && wb1 < HW)
                    v1 = xr[wb1] + xr[wb1 + HW * HW] + xr[wb1 + 2 * HW * HW];
            }
            tile[i] = (uint)f2bf(v0) | ((uint)f2bf(v1) << 16);
        }
    }
    __syncthreads();

    // ---- phase 3: MFMA main loop ----
    const int q  = lane >> 4;      // quad 0..3
    const int n  = lane & 15;      // pixel-col offset within 16-col group / ori for A
    const int qh = q >> 1;         // ky sub-row
    const int kx0 = 8 * (q & 1);

    // A fragments: afrag[c] = K[m=lane&15][k = 32c + q*8 + j]
    //  -> ky = 2c + qh, kx = kx0 + j  (contiguous, 16B aligned)
    short8 afrag[8];
    #pragma unroll
    for (int c = 0; c < 8; ++c) {
        const int ky = 2 * c + qh;
        afrag[c] = *reinterpret_cast<const short8*>(&kwa[((n * 16 + ky) * 16) + kx0]);
    }

    const int pc   = wave * 16;                 // this wave's 16-col group
    const int col0 = pc + n + kx0;              // tile col of fragment start
    const int s    = col0 & 1;                  // which shifted copy
    const int cw   = col0 >> 1;                 // word offset within row
    const uint cbase = (uint)(s * TWORDS + cw);

    #pragma unroll 1
    for (int it = 0; it < 8; ++it) {
        const int pr0 = it * 8;                 // 8 output rows this iteration
        floatx4 acc_e[4], acc_o[4];
        #pragma unroll
        for (int i = 0; i < 4; ++i) { acc_e[i] = (floatx4){0,0,0,0}; acc_o[i] = (floatx4){0,0,0,0}; }

        const uint base0 = cbase + (uint)((pr0 + qh) * WROW);
        #pragma unroll
        for (int t = 0; t < 11; ++t) {
            const uint oe = base0 + (uint)(2 * t * WROW);
            FragU fe, fo;
            fe.u4.x = tile[oe + 0]; fe.u4.y = tile[oe + 1];
            fe.u4.z = tile[oe + 2]; fe.u4.w = tile[oe + 3];
            fo.u4.x = tile[oe + WROW + 0]; fo.u4.y = tile[oe + WROW + 1];
            fo.u4.z = tile[oe + WROW + 2]; fo.u4.w = tile[oe + WROW + 3];
            #pragma unroll
            for (int i = 0; i < 4; ++i) {
                if (t - i >= 0 && t - i < 8) {
                    acc_e[i] = __builtin_amdgcn_mfma_f32_16x16x32_bf16(afrag[t - i], fe.s8, acc_e[i], 0, 0, 0);
                    acc_o[i] = __builtin_amdgcn_mfma_f32_16x16x32_bf16(afrag[t - i], fo.s8, acc_o[i], 0, 0, 0);
                }
            }
        }

        // epilogue: D col = lane&15 = pixel col, row = q*4 + reg = orientation
        if (q < 2) {
            const int wcol = w0 + pc + n;
            float* ob = out + (((size_t)img * NORI + q * 4) << 16) + wcol;
            #pragma unroll
            for (int i = 0; i < 4; ++i) {
                const int he = h0 + pr0 + 2 * i;
                #pragma unroll
                for (int reg = 0; reg < 4; ++reg) {
                    ob[((size_t)reg << 16) + (he << 8)]       = acc_e[i][reg];
                    ob[((size_t)reg << 16) + ((he + 1) << 8)] = acc_o[i][reg];
                }
            }
        }
    }
}

extern "C" void kernel_launch(void* const* d_in, const int* in_sizes, int n_in,
                              void* d_out, int out_size, void* d_ws, size_t ws_size,
                              hipStream_t stream) {
    const float* x     = (const float*)d_in[0];
    const float* theta = (const float*)d_in[1];
    const float* sigma = (const float*)d_in[2];
    const float* lambd = (const float*)d_in[3];
    const float* gamma = (const float*)d_in[4];
    const float* psi   = (const float*)d_in[5];
    float* out = (float*)d_out;

    dim3 grid(HW / TW, HW / TH, 64);   // (4, 4, 64) = 1024 blocks
    gabor_mfma<<<grid, 256, 0, stream>>>(x, theta, sigma, lambd, gamma, psi, out);
}

// Round 3
// 188.342 us; speedup vs baseline: 1.6417x; 1.1054x over previous
//
#include <hip/hip_runtime.h>
#include <math.h>

#define KS    15
#define HALF  7
#define NORI  8
#define HW    256
#define TW    64
#define TH    64
#define WROW  48                 // words per tile row (96 bf16 cols)
#define RT    80                 // tile rows staged
#define TWORDS (RT * WROW)       // 3840 words per copy
#define TB1   (TWORDS + 8)       // copy-1 base: +8 word pad -> +8 bank shift

typedef __attribute__((ext_vector_type(8))) short  short8;
typedef __attribute__((ext_vector_type(4))) float  floatx4;

union FragU { uint4 u4; short8 s8; };

__device__ __forceinline__ ushort f2bf(float f) {
    union { float f; uint u; } a; a.f = f;
    return (ushort)((a.u + 0x7FFFu + ((a.u >> 16) & 1u)) >> 16);
}
__device__ __forceinline__ uint pack2(float lo, float hi) {
    return (uint)f2bf(lo) | ((uint)f2bf(hi) << 16);
}

__global__ __launch_bounds__(256, 4) void gabor_mfma(
    const float* __restrict__ x,
    const float* __restrict__ theta, const float* __restrict__ sigma,
    const float* __restrict__ lambd, const float* __restrict__ gamma,
    const float* __restrict__ psi,
    float* __restrict__ out)
{
    __shared__ uint   tile[2 * TWORDS + 8];   // two col-shifted bf16 copies
    __shared__ ushort kwa[NORI * 16 * 16];    // weights [o][ky16][kx16]

    const int tid  = threadIdx.x;
    const int img  = blockIdx.z;
    const int h0   = blockIdx.y * TH;
    const int w0   = blockIdx.x * TW;
    const int lane = tid & 63;
    const int wave = tid >> 6;

    // ---- zero padded weight array ----
    for (int i = tid; i < NORI * 16 * 16; i += 256) kwa[i] = 0;
    __syncthreads();

    // ---- compute Gabor weights (wave w -> orientations 2w, 2w+1) ----
    #pragma unroll 1
    for (int oo = 0; oo < 2; ++oo) {
        const int o = wave * 2 + oo;
        const float th = theta[o];
        const float sg = fmaxf(sigma[o], 1.0f);
        const float lb = fmaxf(lambd[o], 2.0f);
        const float gm = fminf(fmaxf(gamma[o], 0.1f), 1.0f);
        const float ps = psi[o];
        const float ct = cosf(th), st = sinf(th);
        const float inv_sg2 = 1.0f / (sg * sg);
        const float gm2 = gm * gm;
        const float wfreq = 6.283185307179586f / lb;

        float vals[4];
        float sum = 0.0f, sumsq = 0.0f;
        #pragma unroll
        for (int j = 0; j < 4; ++j) {
            const int t = lane + j * 64;
            float v = 0.0f;
            if (t < KS * KS) {
                const int ky = t / KS, kx = t % KS;
                const float yg = (float)(ky - HALF);
                const float xg = (float)(kx - HALF);
                const float x_th =  xg * ct + yg * st;
                const float y_th = -xg * st + yg * ct;
                const float g = expf(-0.5f * (x_th * x_th + gm2 * y_th * y_th) * inv_sg2);
                v = g * cosf(wfreq * x_th + ps);
                sum += v; sumsq += v * v;
            }
            vals[j] = v;
        }
        #pragma unroll
        for (int off = 32; off > 0; off >>= 1) {
            sum   += __shfl_down(sum,   off);
            sumsq += __shfl_down(sumsq, off);
        }
        sum = __shfl(sum, 0); sumsq = __shfl(sumsq, 0);
        const float nn   = (float)(KS * KS);
        const float mean = sum / nn;
        const float var  = (sumsq - sum * sum / nn) / (nn - 1.0f);
        const float inv  = 1.0f / (sqrtf(var) + 1e-8f);
        #pragma unroll
        for (int j = 0; j < 4; ++j) {
            const int t = lane + j * 64;
            if (t < KS * KS) {
                const int ky = t / KS, kx = t % KS;
                kwa[(o * 16 + ky) * 16 + kx] = f2bf((vals[j] - mean) * inv);
            }
        }
    }

    // ---- stage channel-summed bf16 tile, 2 shifted copies, 1 read/element ----
    // slot (r, j): 4 aligned cols c0 = w0 - 8 + 4j .. +3, j in [0,25)
    {
        const float* xim = x + (size_t)img * 3 * HW * HW;
        for (int slot = tid; slot < RT * 25; slot += 256) {
            const int r  = slot / 25;
            const int j  = slot - r * 25;
            const int h  = h0 + r - HALF;
            const int c0 = w0 - 8 + 4 * j;
            const bool hok = (h >= 0) && (h < HW);
            const float* xr = xim + h * HW;
            float s0, s1, s2, s3;
            if (hok && c0 >= 0 && c0 <= HW - 4) {
                const float4 a = *(const float4*)&xr[c0];
                const float4 b = *(const float4*)&xr[c0 + HW * HW];
                const float4 c = *(const float4*)&xr[c0 + 2 * HW * HW];
                s0 = a.x + b.x + c.x; s1 = a.y + b.y + c.y;
                s2 = a.z + b.z + c.z; s3 = a.w + b.w + c.w;
            } else {
                s0 = s1 = s2 = s3 = 0.0f;
                if (hok) {
                    #pragma unroll
                    for (int k = 0; k < 4; ++k) {
                        const int c = c0 + k;
                        if (c >= 0 && c < HW) {
                            const float v = xr[c] + xr[c + HW * HW] + xr[c + 2 * HW * HW];
                            if (k == 0) s0 = v; else if (k == 1) s1 = v;
                            else if (k == 2) s2 = v; else s3 = v;
                        }
                    }
                }
            }
            // s4 = first element of next slot (same row); j==24 never needs it
            float s4 = __shfl(s0, lane + 1);
            if (lane == 63 && j < 24) {
                const int c = c0 + 4;
                s4 = 0.0f;
                if (hok && c >= 0 && c < HW)
                    s4 = xr[c] + xr[c + HW * HW] + xr[c + 2 * HW * HW];
            }
            // copy0 word wc covers cols (2wc-7, 2wc-6); copy1: (2wc-6, 2wc-5)
            const int rb = r * WROW;
            const int w0c = 2 * j;          // copy0: (s1,s2)@2j, (s3,s4)@2j+1
            if (w0c < WROW)     tile[rb + w0c]           = pack2(s1, s2);
            if (w0c + 1 < WROW) tile[rb + w0c + 1]       = pack2(s3, s4);
            const int w1c = 2 * j - 1;      // copy1: (s0,s1)@2j-1, (s2,s3)@2j
            if (w1c >= 0 && w1c < WROW) tile[TB1 + rb + w1c]     = pack2(s0, s1);
            if (w1c + 1 < WROW)         tile[TB1 + rb + w1c + 1] = pack2(s2, s3);
        }
    }
    __syncthreads();

    // ---- MFMA main loop: packed A (rows 0-7 = ori, rows 8-15 = ori shifted 1 ky) ----
    const int q   = lane >> 4;       // quad
    const int n   = lane & 15;
    const int qh  = q >> 1;
    const int kx0 = 8 * (q & 1);
    const int o   = n & 7;           // A row m=n: orientation
    const int p   = n >> 3;          // row-shift

    short8 afrag[8];
    #pragma unroll
    for (int c = 0; c < 8; ++c) {
        const int kyi = (2 * c + qh - p) & 15;   // -1 wraps to 15 (zero row)
        afrag[c] = *reinterpret_cast<const short8*>(&kwa[(o * 16 + kyi) * 16 + kx0]);
    }

    const int pc   = wave * 16;
    const int col0 = pc + n + kx0;
    const uint cbase = (uint)((col0 & 1) * TB1 + (col0 >> 1));

    #pragma unroll 1
    for (int it = 0; it < 4; ++it) {
        const int pr0 = it * 16;     // 8 row-pairs = 16 output rows per it
        floatx4 acc[8];
        #pragma unroll
        for (int i = 0; i < 8; ++i) acc[i] = (floatx4){0, 0, 0, 0};

        const uint rb = cbase + (uint)((pr0 + qh) * WROW);
        #pragma unroll
        for (int t = 0; t < 15; ++t) {
            const uint oe = rb + (uint)(2 * t * WROW);
            FragU f;
            f.u4.x = tile[oe];     f.u4.y = tile[oe + 1];
            f.u4.z = tile[oe + 2]; f.u4.w = tile[oe + 3];
            #pragma unroll
            for (int i = 0; i < 8; ++i) {
                if (t - i >= 0 && t - i < 8)
                    acc[i] = __builtin_amdgcn_mfma_f32_16x16x32_bf16(afrag[t - i], f.s8, acc[i], 0, 0, 0);
            }
        }

        // D: col = lane&15 = pixel col; row m = q*4+reg -> o = m&7, p = m>>3
        const int wcol = w0 + pc + n;
        #pragma unroll
        for (int i = 0; i < 8; ++i) {
            const int H = h0 + pr0 + 2 * i;
            #pragma unroll
            for (int reg = 0; reg < 4; ++reg) {
                const int m  = q * 4 + reg;
                const int om = m & 7, pm = m >> 3;
                out[(((size_t)img * NORI + om) << 16) + ((size_t)(H + pm) << 8) + wcol] = acc[i][reg];
            }
        }
    }
}

extern "C" void kernel_launch(void* const* d_in, const int* in_sizes, int n_in,
                              void* d_out, int out_size, void* d_ws, size_t ws_size,
                              hipStream_t stream) {
    const float* x     = (const float*)d_in[0];
    const float* theta = (const float*)d_in[1];
    const float* sigma = (const float*)d_in[2];
    const float* lambd = (const float*)d_in[3];
    const float* gamma = (const float*)d_in[4];
    const float* psi   = (const float*)d_in[5];
    float* out = (float*)d_out;

    dim3 grid(HW / TW, HW / TH, 64);   // (4, 4, 64) = 1024 blocks
    gabor_mfma<<<grid, 256, 0, stream>>>(x, theta, sigma, lambd, gamma, psi, out);
}